// Round 6
// baseline (241.442 us; speedup 1.0000x reference)
//
#include <hip/hip_runtime.h>
#include <hip/hip_bf16.h>
#include <math.h>

typedef __attribute__((ext_vector_type(8))) short  short8;
typedef __attribute__((ext_vector_type(4))) short  short4v;
typedef __attribute__((ext_vector_type(4))) float  floatx4;

// async global->LDS, 16B per lane; LDS dest = wave-uniform base + lane*16
#define GLD16(gp, lp) __builtin_amdgcn_global_load_lds( \
    (__attribute__((address_space(1))) void*)(void*)(gp), \
    (__attribute__((address_space(3))) void*)(lp), 16, 0, 0)

// ---------------------------------------------------------------------------
// Shared m97-style bf16 GEMM core: C = A[M,K] * Bt[N,K]^T, fp32 acc.
// 128x128 tile, 4 waves (2x2), 4x4 16x16x32 MFMA per wave, BK=64,
// global_load_lds width-16 staging, XOR chunk swizzle (chunk c of row r holds
// global chunk c^(r&7)) -> ds_read_b128 fragment reads are 2-way (free).
// MODE 1: QKV projection. +bias; n0<2048 -> bf16 C store; n0>=2048 -> V part,
//         written TRANSPOSED (via LDS bounce) into VT[b][d][s], bf16.
// MODE 2: scores. epilogue e=exp(acc*scale) -> bf16 Pu store + per-row
//         partial sums atomicAdd'ed into rowsum (offset-free softmax).
// MODE 3: PV. epilogue out = acc / rowsum[row], fp32 store.
// ---------------------------------------------------------------------------
template <int MODE>
__global__ __launch_bounds__(256, 2)
void gemm_bt(const unsigned short* __restrict__ A,
             const unsigned short* __restrict__ Bt,
             const float* __restrict__ bias,
             void* __restrict__ Cout,
             int lda, int ldb, int ldc, int K,
             long sA, long sB, long sC,
             float scale,
             unsigned short* __restrict__ VT,
             float* __restrict__ rowsum)
{
    __shared__ __align__(16) unsigned short smem[16384];   // 32 KB
    unsigned short* As = smem;
    unsigned short* Bs = smem + 8192;

    const int z = blockIdx.z;
    A  += (long)z * sA;
    Bt += (long)z * sB;

    const int m0 = blockIdx.y * 128;
    const int n0 = blockIdx.x * 128;

    const int t   = threadIdx.x;
    const int w   = t >> 6;
    const int l15 = t & 15;
    const int lq  = (t & 63) >> 4;
    const int wm  = w >> 1;
    const int wn  = w & 1;

    // staging: LDS chunk cid=(r*8+c) <- global chunk (r, c^(r&7)); 16B chunks
    long gOffA[4], gOffB[4];
    int  lOff[4];
#pragma unroll
    for (int i = 0; i < 4; ++i) {
        int cid = i * 256 + t;
        int r   = cid >> 3;
        int c   = cid & 7;
        int cg  = c ^ (r & 7);
        lOff[i]  = cid * 8;
        gOffA[i] = (long)(m0 + r) * lda + cg * 8;
        gOffB[i] = (long)(n0 + r) * ldb + cg * 8;
    }

    floatx4 acc[4][4];
#pragma unroll
    for (int i = 0; i < 4; ++i)
#pragma unroll
        for (int j = 0; j < 4; ++j)
            acc[i][j] = (floatx4){0.f, 0.f, 0.f, 0.f};

    for (int k0 = 0; k0 < K; k0 += 64) {
#pragma unroll
        for (int i = 0; i < 4; ++i) {
            GLD16(A  + gOffA[i] + k0, &As[lOff[i]]);
            GLD16(Bt + gOffB[i] + k0, &Bs[lOff[i]]);
        }
        __syncthreads();   // vmcnt drained -> staging visible

#pragma unroll
        for (int s = 0; s < 2; ++s) {
            short8 af[4], bf[4];
#pragma unroll
            for (int mt = 0; mt < 4; ++mt) {
                int r  = wm * 64 + mt * 16 + l15;
                int cc = (s * 4 + lq) ^ (r & 7);
                af[mt] = *(const short8*)&As[r * 64 + cc * 8];
            }
#pragma unroll
            for (int nt = 0; nt < 4; ++nt) {
                int r  = wn * 64 + nt * 16 + l15;
                int cc = (s * 4 + lq) ^ (r & 7);
                bf[nt] = *(const short8*)&Bs[r * 64 + cc * 8];
            }
#pragma unroll
            for (int mt = 0; mt < 4; ++mt)
#pragma unroll
                for (int nt = 0; nt < 4; ++nt)
                    acc[mt][nt] = __builtin_amdgcn_mfma_f32_16x16x32_bf16(
                        af[mt], bf[nt], acc[mt][nt], 0, 0, 0);
        }
        __syncthreads();   // fragment reads done before next staging
    }

    // ---------------- epilogues (C/D layout: col=lane&15, row=quad*4+reg) ----
    if (MODE == 1) {
        if (n0 < 2048) {
            // Q/K part: plain bf16 store with bias
#pragma unroll
            for (int nt = 0; nt < 4; ++nt) {
                int n = n0 + wn * 64 + nt * 16 + l15;
                float bb = bias[n];
#pragma unroll
                for (int mt = 0; mt < 4; ++mt) {
                    int mBase = m0 + wm * 64 + mt * 16 + lq * 4;
#pragma unroll
                    for (int r = 0; r < 4; ++r) {
                        float v = acc[mt][nt][r] + bb;
                        ((__hip_bfloat16*)Cout)[(long)(mBase + r) * ldc + n] =
                            __float2bfloat16(v);
                    }
                }
            }
        } else {
            // V part: transpose via LDS into VT[b][d][s] (d = n-2048, s = m%2048)
            const int  z2  = m0 >> 11;
            const int  s0l = m0 & 2047;
            const int  d0  = n0 - 2048;
            __hip_bfloat16* T = (__hip_bfloat16*)smem;   // [64][136]
#pragma unroll
            for (int p = 0; p < 2; ++p) {
                __syncthreads();
                if (wn == p) {
#pragma unroll
                    for (int nt = 0; nt < 4; ++nt) {
                        int nl = nt * 16 + l15;           // 0..63
                        float bb = bias[n0 + p * 64 + nl];
#pragma unroll
                        for (int mt = 0; mt < 4; ++mt)
#pragma unroll
                            for (int r = 0; r < 4; ++r) {
                                int ml = wm * 64 + mt * 16 + lq * 4 + r;
                                T[nl * 136 + ml] =
                                    __float2bfloat16(acc[mt][nt][r] + bb);
                            }
                    }
                }
                __syncthreads();
#pragma unroll
                for (int pass = 0; pass < 4; ++pass) {
                    int row = pass * 16 + (t >> 4);       // 0..63
                    int mc  = (t & 15) * 8;
                    short8 val = *(const short8*)&T[row * 136 + mc];
                    *(short8*)&VT[(long)z2 * (1024L * 2048) +
                                  (long)(d0 + p * 64 + row) * 2048 + s0l + mc] = val;
                }
            }
        }
    } else if (MODE == 2) {
        float* rs = rowsum + (long)z * 2048;
#pragma unroll
        for (int mt = 0; mt < 4; ++mt) {
#pragma unroll
            for (int r = 0; r < 4; ++r) {
                int m = m0 + wm * 64 + mt * 16 + lq * 4 + r;
                float psum = 0.f;
#pragma unroll
                for (int nt = 0; nt < 4; ++nt) {
                    int n = n0 + wn * 64 + nt * 16 + l15;
                    float e = __expf(acc[mt][nt][r] * scale);
                    __hip_bfloat16 eb = __float2bfloat16(e);
                    ((__hip_bfloat16*)Cout)[(long)z * sC + (long)m * ldc + n] = eb;
                    psum += __bfloat162float(eb);   // sum the rounded values
                }
                psum += __shfl_xor(psum, 1);
                psum += __shfl_xor(psum, 2);
                psum += __shfl_xor(psum, 4);
                psum += __shfl_xor(psum, 8);
                if (l15 == 0) atomicAdd(&rs[m], psum);
            }
        }
    } else {   // MODE 3
        const float* rs = rowsum + (long)z * 2048;
#pragma unroll
        for (int mt = 0; mt < 4; ++mt) {
            int mBase = m0 + wm * 64 + mt * 16 + lq * 4;
            float inv[4];
#pragma unroll
            for (int r = 0; r < 4; ++r) inv[r] = 1.0f / rs[mBase + r];
#pragma unroll
            for (int nt = 0; nt < 4; ++nt) {
                int n = n0 + wn * 64 + nt * 16 + l15;
#pragma unroll
                for (int r = 0; r < 4; ++r)
                    ((float*)Cout)[(long)z * sC + (long)(mBase + r) * ldc + n] =
                        acc[mt][nt][r] * inv[r];
            }
        }
    }
}

// ---------------------------------------------------------------------------
// mega-prep: one dispatch doing (by blockIdx range):
//   [0, 8192)            : cast x fp32 -> bf16 (4 elems/thread)
//   [8192, 11264)        : W^T + cast for Wq/Wk/Wv -> WT3 (32x32 tiles)
//   [11264, 11276)       : bias concat -> bc[3072]
//   [11276]              : zero rowsum[8192]
// ---------------------------------------------------------------------------
__global__ __launch_bounds__(256)
void prep(const float* __restrict__ x,
          const float* __restrict__ Wq, const float* __restrict__ Wk,
          const float* __restrict__ Wv,
          const float* __restrict__ bq, const float* __restrict__ bk,
          const float* __restrict__ bv,
          __hip_bfloat16* __restrict__ xbf,
          __hip_bfloat16* __restrict__ WT3,
          float* __restrict__ bc,
          float* __restrict__ rs)
{
    __shared__ float tile[32][33];
    const int b = blockIdx.x;
    const int t = threadIdx.x;

    if (b < 8192) {
        long i = ((long)b * 256 + t) * 4;
        float4 v = *(const float4*)(x + i);
        union { short4v s; __hip_bfloat16 h[4]; } u;
        u.h[0] = __float2bfloat16(v.x);
        u.h[1] = __float2bfloat16(v.y);
        u.h[2] = __float2bfloat16(v.z);
        u.h[3] = __float2bfloat16(v.w);
        *(short4v*)(xbf + i) = u.s;
    } else if (b < 8192 + 3072) {
        const int idx = b - 8192;
        const int zz  = idx >> 10;
        const int rem = idx & 1023;
        const float* src = (zz == 0) ? Wq : (zz == 1) ? Wk : Wv;
        __hip_bfloat16* dst = WT3 + (long)zz * 1048576;
        const int c0 = (rem & 31) * 32, r0 = (rem >> 5) * 32;
        const int tx = t & 31, ty = t >> 5;   // (32, 8)
#pragma unroll
        for (int i = 0; i < 4; ++i)
            tile[ty + 8 * i][tx] = src[(long)(r0 + ty + 8 * i) * 1024 + c0 + tx];
        __syncthreads();
#pragma unroll
        for (int i = 0; i < 4; ++i)
            dst[(long)(c0 + ty + 8 * i) * 1024 + r0 + tx] =
                __float2bfloat16(tile[tx][ty + 8 * i]);
    } else if (b < 8192 + 3072 + 12) {
        int i = (b - (8192 + 3072)) * 256 + t;
        bc[i] = (i < 1024) ? bq[i] : (i < 2048) ? bk[i - 1024] : bv[i - 2048];
    } else {
#pragma unroll
        for (int i = 0; i < 32; ++i)
            rs[t + 256 * i] = 0.f;
    }
}

// ---------------------------------------------------------------------------
// Inputs/outputs fp32. B=4, S=2048, D=1024.  4 dispatches total.
// ws (MB): QKV bf16 [8192][3072] @0 (48) | VT bf16 4x[1024][2048] @48 (16)
//          WT3 @64 (6) | bc @70 (12KB) | rowsum @70+16KB (32KB)
//          xbf @72 (16) | Pu bf16 4x[2048][2048] @72 (32, overlays dead xbf)
// total 104 MB.
// ---------------------------------------------------------------------------
extern "C" void kernel_launch(void* const* d_in, const int* in_sizes, int n_in,
                              void* d_out, int out_size, void* d_ws, size_t ws_size,
                              hipStream_t stream)
{
    const float* x  = (const float*)d_in[0];
    const float* Wq = (const float*)d_in[1];
    const float* bq = (const float*)d_in[2];
    const float* Wk = (const float*)d_in[3];
    const float* bk = (const float*)d_in[4];
    const float* Wv = (const float*)d_in[5];
    const float* bv = (const float*)d_in[6];

    char* ws = (char*)d_ws;
    const long MB = 1048576;
    __hip_bfloat16* QKV = (__hip_bfloat16*)(ws);
    unsigned short* VT  = (unsigned short*)(ws + 48 * MB);
    __hip_bfloat16* WT3 = (__hip_bfloat16*)(ws + 64 * MB);
    float*          bc  = (float*)         (ws + 70 * MB);
    float*          rs  = (float*)         (ws + 70 * MB + 16384);
    __hip_bfloat16* xbf = (__hip_bfloat16*)(ws + 72 * MB);
    __hip_bfloat16* Pu  = (__hip_bfloat16*)(ws + 72 * MB);   // overlays xbf

    // 1. mega-prep (cast + W^T x3 + bias concat + rowsum zero)
    prep<<<8192 + 3072 + 12 + 1, 256, 0, stream>>>(
        x, Wq, Wk, Wv, bq, bk, bv, xbf, WT3, bc, rs);

    // 2. fused QKV projection (V part written transposed into VT)
    gemm_bt<1><<<dim3(24, 64, 1), 256, 0, stream>>>(
        (const unsigned short*)xbf, (const unsigned short*)WT3, bc, QKV,
        1024, 1024, 3072, 1024, 0, 0, 0, 1.f, VT, nullptr);

    // 3. scores + exp + rowsum: Pu_b = exp(Q_b K_b^T / sqrt(128)), bf16
    gemm_bt<2><<<dim3(16, 16, 4), 256, 0, stream>>>(
        (const unsigned short*)QKV, (const unsigned short*)(QKV + 1024),
        nullptr, Pu,
        3072, 3072, 2048, 1024,
        2048L * 3072, 2048L * 3072, 2048L * 2048,
        0.08838834764831845f, nullptr, rs);

    // 4. PV + normalize: out_b = (Pu_b V_b) / rowsum, fp32
    gemm_bt<3><<<dim3(8, 16, 4), 256, 0, stream>>>(
        (const unsigned short*)Pu, VT, nullptr, (float*)d_out,
        2048, 2048, 1024, 2048,
        2048L * 2048, 1024L * 2048, 2048L * 1024,
        1.f, nullptr, rs);
}

// Round 7
// 224.506 us; speedup vs baseline: 1.0754x; 1.0754x over previous
//
#include <hip/hip_runtime.h>
#include <hip/hip_bf16.h>
#include <math.h>

typedef __attribute__((ext_vector_type(8))) short  short8;
typedef __attribute__((ext_vector_type(4))) short  short4v;
typedef __attribute__((ext_vector_type(4))) float  floatx4;

// async global->LDS, 16B per lane; LDS dest = wave-uniform base + lane*16
#define GLD16(gp, lp) __builtin_amdgcn_global_load_lds( \
    (__attribute__((address_space(1))) void*)(void*)(gp), \
    (__attribute__((address_space(3))) void*)(lp), 16, 0, 0)

// ---------------------------------------------------------------------------
// Shared m97-style bf16 GEMM core: C = A[M,K] * Bt[N,K]^T, fp32 acc.
// 128x128 tile, 4 waves (2x2), 4x4 16x16x32 MFMA per wave, BK=64,
// global_load_lds width-16 staging, XOR chunk swizzle -> conflict-free LDS.
// XCD-aware tile swizzle: flat tile f -> xcd=f&7 (HW round-robin class),
// s=f>>3; each XCD gets a compact PX x PY rectangle of tiles so its private
// L2 sees a small, reused working set (A-stripes were being re-fetched by
// all 8 XCDs before: PV A-traffic ~8x unique).
// MODE 1: QKV projection (+bias; V part stored transposed into VT via LDS).
// MODE 2: scores -> e=exp(acc*scale) bf16 + rowsum atomics (offset-free sm).
// MODE 3: PV -> acc / rowsum, fp32.
// ---------------------------------------------------------------------------
template <int MODE>
__global__ __launch_bounds__(256, 2)
void gemm_bt(const unsigned short* __restrict__ A,
             const unsigned short* __restrict__ Bt,
             const float* __restrict__ bias,
             void* __restrict__ Cout,
             int lda, int ldb, int ldc, int K,
             long sA, long sB, long sC,
             float scale,
             unsigned short* __restrict__ VT,
             float* __restrict__ rowsum)
{
    __shared__ __align__(16) unsigned short smem[16384];   // 32 KB
    unsigned short* As = smem;
    unsigned short* Bs = smem + 8192;

    const int z = blockIdx.z;
    A  += (long)z * sA;
    Bt += (long)z * sB;

    // ---- XCD-aware tile swizzle (per-z tile counts are multiples of 8) ----
    int tx_, ty_;
    {
        const int GX  = gridDim.x;
        const int f   = blockIdx.y * GX + blockIdx.x;
        const int xcd = f & 7;
        const int s   = f >> 3;
        if (MODE == 1) {        // 24 x 64 tiles -> rect 12x16, rects 2x4
            tx_ = (xcd & 1) * 12 + s % 12;
            ty_ = (xcd >> 1) * 16 + s / 12;
        } else if (MODE == 2) { // 16 x 16 tiles -> rect 4x8, rects 4x2
            tx_ = (xcd & 3) * 4 + (s & 3);
            ty_ = (xcd >> 2) * 8 + (s >> 2);
        } else {                // 8 x 16 tiles -> rect 4x4, rects 2x4
            tx_ = (xcd & 1) * 4 + (s & 3);
            ty_ = (xcd >> 1) * 4 + (s >> 2);
        }
    }
    const int m0 = ty_ * 128;
    const int n0 = tx_ * 128;

    const int t   = threadIdx.x;
    const int w   = t >> 6;
    const int l15 = t & 15;
    const int lq  = (t & 63) >> 4;
    const int wm  = w >> 1;
    const int wn  = w & 1;

    // staging: LDS chunk cid=(r*8+c) <- global chunk (r, c^(r&7)); 16B chunks
    long gOffA[4], gOffB[4];
    int  lOff[4];
#pragma unroll
    for (int i = 0; i < 4; ++i) {
        int cid = i * 256 + t;
        int r   = cid >> 3;
        int c   = cid & 7;
        int cg  = c ^ (r & 7);
        lOff[i]  = cid * 8;
        gOffA[i] = (long)(m0 + r) * lda + cg * 8;
        gOffB[i] = (long)(n0 + r) * ldb + cg * 8;
    }

    floatx4 acc[4][4];
#pragma unroll
    for (int i = 0; i < 4; ++i)
#pragma unroll
        for (int j = 0; j < 4; ++j)
            acc[i][j] = (floatx4){0.f, 0.f, 0.f, 0.f};

    for (int k0 = 0; k0 < K; k0 += 64) {
#pragma unroll
        for (int i = 0; i < 4; ++i) {
            GLD16(A  + gOffA[i] + k0, &As[lOff[i]]);
            GLD16(Bt + gOffB[i] + k0, &Bs[lOff[i]]);
        }
        __syncthreads();   // vmcnt drained -> staging visible

#pragma unroll
        for (int s = 0; s < 2; ++s) {
            short8 af[4], bf[4];
#pragma unroll
            for (int mt = 0; mt < 4; ++mt) {
                int r  = wm * 64 + mt * 16 + l15;
                int cc = (s * 4 + lq) ^ (r & 7);
                af[mt] = *(const short8*)&As[r * 64 + cc * 8];
            }
#pragma unroll
            for (int nt = 0; nt < 4; ++nt) {
                int r  = wn * 64 + nt * 16 + l15;
                int cc = (s * 4 + lq) ^ (r & 7);
                bf[nt] = *(const short8*)&Bs[r * 64 + cc * 8];
            }
#pragma unroll
            for (int mt = 0; mt < 4; ++mt)
#pragma unroll
                for (int nt = 0; nt < 4; ++nt)
                    acc[mt][nt] = __builtin_amdgcn_mfma_f32_16x16x32_bf16(
                        af[mt], bf[nt], acc[mt][nt], 0, 0, 0);
        }
        __syncthreads();   // fragment reads done before next staging
    }

    // ---------------- epilogues (C/D layout: col=lane&15, row=quad*4+reg) ----
    if (MODE == 1) {
        if (n0 < 2048) {
            // Q/K part: plain bf16 store with bias
#pragma unroll
            for (int nt = 0; nt < 4; ++nt) {
                int n = n0 + wn * 64 + nt * 16 + l15;
                float bb = bias[n];
#pragma unroll
                for (int mt = 0; mt < 4; ++mt) {
                    int mBase = m0 + wm * 64 + mt * 16 + lq * 4;
#pragma unroll
                    for (int r = 0; r < 4; ++r) {
                        float v = acc[mt][nt][r] + bb;
                        ((__hip_bfloat16*)Cout)[(long)(mBase + r) * ldc + n] =
                            __float2bfloat16(v);
                    }
                }
            }
        } else {
            // V part: transpose via LDS into VT[b][d][s] (d = n-2048, s = m%2048)
            const int  z2  = m0 >> 11;
            const int  s0l = m0 & 2047;
            const int  d0  = n0 - 2048;
            __hip_bfloat16* T = (__hip_bfloat16*)smem;   // [64][136]
#pragma unroll
            for (int p = 0; p < 2; ++p) {
                __syncthreads();
                if (wn == p) {
#pragma unroll
                    for (int nt = 0; nt < 4; ++nt) {
                        int nl = nt * 16 + l15;           // 0..63
                        float bb = bias[n0 + p * 64 + nl];
#pragma unroll
                        for (int mt = 0; mt < 4; ++mt)
#pragma unroll
                            for (int r = 0; r < 4; ++r) {
                                int ml = wm * 64 + mt * 16 + lq * 4 + r;
                                T[nl * 136 + ml] =
                                    __float2bfloat16(acc[mt][nt][r] + bb);
                            }
                    }
                }
                __syncthreads();
#pragma unroll
                for (int pass = 0; pass < 4; ++pass) {
                    int row = pass * 16 + (t >> 4);       // 0..63
                    int mc  = (t & 15) * 8;
                    short8 val = *(const short8*)&T[row * 136 + mc];
                    *(short8*)&VT[(long)z2 * (1024L * 2048) +
                                  (long)(d0 + p * 64 + row) * 2048 + s0l + mc] = val;
                }
            }
        }
    } else if (MODE == 2) {
        float* rs = rowsum + (long)z * 2048;
#pragma unroll
        for (int mt = 0; mt < 4; ++mt) {
#pragma unroll
            for (int r = 0; r < 4; ++r) {
                int m = m0 + wm * 64 + mt * 16 + lq * 4 + r;
                float psum = 0.f;
#pragma unroll
                for (int nt = 0; nt < 4; ++nt) {
                    int n = n0 + wn * 64 + nt * 16 + l15;
                    float e = __expf(acc[mt][nt][r] * scale);
                    __hip_bfloat16 eb = __float2bfloat16(e);
                    ((__hip_bfloat16*)Cout)[(long)z * sC + (long)m * ldc + n] = eb;
                    psum += __bfloat162float(eb);   // sum the rounded values
                }
                psum += __shfl_xor(psum, 1);
                psum += __shfl_xor(psum, 2);
                psum += __shfl_xor(psum, 4);
                psum += __shfl_xor(psum, 8);
                if (l15 == 0) atomicAdd(&rs[m], psum);
            }
        }
    } else {   // MODE 3
        const float* rs = rowsum + (long)z * 2048;
#pragma unroll
        for (int mt = 0; mt < 4; ++mt) {
            int mBase = m0 + wm * 64 + mt * 16 + lq * 4;
            float inv[4];
#pragma unroll
            for (int r = 0; r < 4; ++r) inv[r] = 1.0f / rs[mBase + r];
#pragma unroll
            for (int nt = 0; nt < 4; ++nt) {
                int n = n0 + wn * 64 + nt * 16 + l15;
#pragma unroll
                for (int r = 0; r < 4; ++r)
                    ((float*)Cout)[(long)z * sC + (long)(mBase + r) * ldc + n] =
                        acc[mt][nt][r] * inv[r];
            }
        }
    }
}

// ---------------------------------------------------------------------------
// mega-prep: one dispatch doing (by blockIdx range):
//   [0, 8192)            : cast x fp32 -> bf16 (4 elems/thread)
//   [8192, 11264)        : W^T + cast for Wq/Wk/Wv -> WT3 (32x32 tiles)
//   [11264, 11276)       : bias concat -> bc[3072]
//   [11276]              : zero rowsum[8192]
// ---------------------------------------------------------------------------
__global__ __launch_bounds__(256)
void prep(const float* __restrict__ x,
          const float* __restrict__ Wq, const float* __restrict__ Wk,
          const float* __restrict__ Wv,
          const float* __restrict__ bq, const float* __restrict__ bk,
          const float* __restrict__ bv,
          __hip_bfloat16* __restrict__ xbf,
          __hip_bfloat16* __restrict__ WT3,
          float* __restrict__ bc,
          float* __restrict__ rs)
{
    __shared__ float tile[32][33];
    const int b = blockIdx.x;
    const int t = threadIdx.x;

    if (b < 8192) {
        long i = ((long)b * 256 + t) * 4;
        float4 v = *(const float4*)(x + i);
        union { short4v s; __hip_bfloat16 h[4]; } u;
        u.h[0] = __float2bfloat16(v.x);
        u.h[1] = __float2bfloat16(v.y);
        u.h[2] = __float2bfloat16(v.z);
        u.h[3] = __float2bfloat16(v.w);
        *(short4v*)(xbf + i) = u.s;
    } else if (b < 8192 + 3072) {
        const int idx = b - 8192;
        const int zz  = idx >> 10;
        const int rem = idx & 1023;
        const float* src = (zz == 0) ? Wq : (zz == 1) ? Wk : Wv;
        __hip_bfloat16* dst = WT3 + (long)zz * 1048576;
        const int c0 = (rem & 31) * 32, r0 = (rem >> 5) * 32;
        const int tx = t & 31, ty = t >> 5;   // (32, 8)
#pragma unroll
        for (int i = 0; i < 4; ++i)
            tile[ty + 8 * i][tx] = src[(long)(r0 + ty + 8 * i) * 1024 + c0 + tx];
        __syncthreads();
#pragma unroll
        for (int i = 0; i < 4; ++i)
            dst[(long)(c0 + ty + 8 * i) * 1024 + r0 + tx] =
                __float2bfloat16(tile[tx][ty + 8 * i]);
    } else if (b < 8192 + 3072 + 12) {
        int i = (b - (8192 + 3072)) * 256 + t;
        bc[i] = (i < 1024) ? bq[i] : (i < 2048) ? bk[i - 1024] : bv[i - 2048];
    } else {
#pragma unroll
        for (int i = 0; i < 32; ++i)
            rs[t + 256 * i] = 0.f;
    }
}

// ---------------------------------------------------------------------------
// Inputs/outputs fp32. B=4, S=2048, D=1024.  4 dispatches total.
// ws (MB): QKV bf16 [8192][3072] @0 (48) | VT bf16 4x[1024][2048] @48 (16)
//          WT3 @64 (6) | bc @70 (12KB) | rowsum @70+16KB (32KB)
//          xbf @72 (16) | Pu bf16 4x[2048][2048] @72 (32, overlays dead xbf)
// total 104 MB.
// ---------------------------------------------------------------------------
extern "C" void kernel_launch(void* const* d_in, const int* in_sizes, int n_in,
                              void* d_out, int out_size, void* d_ws, size_t ws_size,
                              hipStream_t stream)
{
    const float* x  = (const float*)d_in[0];
    const float* Wq = (const float*)d_in[1];
    const float* bq = (const float*)d_in[2];
    const float* Wk = (const float*)d_in[3];
    const float* bk = (const float*)d_in[4];
    const float* Wv = (const float*)d_in[5];
    const float* bv = (const float*)d_in[6];

    char* ws = (char*)d_ws;
    const long MB = 1048576;
    __hip_bfloat16* QKV = (__hip_bfloat16*)(ws);
    unsigned short* VT  = (unsigned short*)(ws + 48 * MB);
    __hip_bfloat16* WT3 = (__hip_bfloat16*)(ws + 64 * MB);
    float*          bc  = (float*)         (ws + 70 * MB);
    float*          rs  = (float*)         (ws + 70 * MB + 16384);
    __hip_bfloat16* xbf = (__hip_bfloat16*)(ws + 72 * MB);
    __hip_bfloat16* Pu  = (__hip_bfloat16*)(ws + 72 * MB);   // overlays xbf

    // 1. mega-prep (cast + W^T x3 + bias concat + rowsum zero)
    prep<<<8192 + 3072 + 12 + 1, 256, 0, stream>>>(
        x, Wq, Wk, Wv, bq, bk, bv, xbf, WT3, bc, rs);

    // 2. fused QKV projection (V part written transposed into VT)
    gemm_bt<1><<<dim3(24, 64, 1), 256, 0, stream>>>(
        (const unsigned short*)xbf, (const unsigned short*)WT3, bc, QKV,
        1024, 1024, 3072, 1024, 0, 0, 0, 1.f, VT, nullptr);

    // 3. scores + exp + rowsum: Pu_b = exp(Q_b K_b^T / sqrt(128)), bf16
    gemm_bt<2><<<dim3(16, 16, 4), 256, 0, stream>>>(
        (const unsigned short*)QKV, (const unsigned short*)(QKV + 1024),
        nullptr, Pu,
        3072, 3072, 2048, 1024,
        2048L * 3072, 2048L * 3072, 2048L * 2048,
        0.08838834764831845f, nullptr, rs);

    // 4. PV + normalize: out_b = (Pu_b V_b) / rowsum, fp32
    gemm_bt<3><<<dim3(8, 16, 4), 256, 0, stream>>>(
        (const unsigned short*)Pu, VT, nullptr, (float*)d_out,
        2048, 2048, 1024, 2048,
        2048L * 2048, 1024L * 2048, 2048L * 1024,
        1.f, nullptr, rs);
}